// Round 8
// baseline (1565.927 us; speedup 1.0000x reference)
//
#include <hip/hip_runtime.h>
#include <math.h>

#define BATCH   4
#define SEQ     2048
#define DMODEL  768
#define DSTATE  16
#define DCONV   4
#define HEADDIM 64
#define DINNER  1536
#define NHEADS  24
#define CONVDIM 1568
#define DINPROJ 3128
#define DFFN    3072
#define ROWS    (BATCH*SEQ)   // 8192
#define QCH     128           // scan chunk length
#define NCHUNK  (SEQ/QCH)     // 16

typedef __attribute__((ext_vector_type(8)))  short bhalf8;    // 8 bf16 (4 VGPRs)
typedef __attribute__((ext_vector_type(16))) float floatx16;  // 32x32 acc

__device__ __forceinline__ float gelu_f(float x) {
    return 0.5f * x * (1.0f + erff(x * 0.70710678118654752f));
}

// truncation split: v ~= hi + lo (bf16 each), error ~2^-16 rel
__device__ __forceinline__ void splitT(float v, unsigned short& h, unsigned short& l) {
    unsigned u = __float_as_uint(v);
    h = (unsigned short)(u >> 16);
    float rem = v - __uint_as_float(u & 0xFFFF0000u);
    l = (unsigned short)(__float_as_uint(rem) >> 16);
}

// ---------------- block reduction (256 threads, wave64) ----------------
__device__ __forceinline__ float2 blockReduce2(float a, float b) {
    #pragma unroll
    for (int o = 32; o > 0; o >>= 1) {
        a += __shfl_down(a, o, 64);
        b += __shfl_down(b, o, 64);
    }
    __shared__ float sa[4], sb[4];
    int w = threadIdx.x >> 6, lane = threadIdx.x & 63;
    if (lane == 0) { sa[w] = a; sb[w] = b; }
    __syncthreads();
    if (threadIdx.x == 0) {
        int nw = blockDim.x >> 6;
        for (int i = 1; i < nw; ++i) { a += sa[i]; b += sb[i]; }
        sa[0] = a; sb[0] = b;
    }
    __syncthreads();
    return make_float2(sa[0], sb[0]);
}

// ---------------- LayerNorm (optionally with residual add) ----------------
__global__ __launch_bounds__(256) void ln_kernel(
    const float* __restrict__ x, const float* __restrict__ res,
    const float* __restrict__ w, const float* __restrict__ b,
    float* __restrict__ out)
{
    int r = blockIdx.x;
    const float* xr = x + (size_t)r * DMODEL;
    float v[3]; float s = 0.f, ss = 0.f;
    #pragma unroll
    for (int i = 0; i < 3; ++i) {
        int c = threadIdx.x + i * 256;
        float t = xr[c];
        if (res) t += res[(size_t)r * DMODEL + c];
        v[i] = t; s += t; ss += t * t;
    }
    float2 red = blockReduce2(s, ss);
    float mean = red.x * (1.0f / DMODEL);
    float var  = red.y * (1.0f / DMODEL) - mean * mean;
    float inv  = rsqrtf(var + 1e-5f);
    #pragma unroll
    for (int i = 0; i < 3; ++i) {
        int c = threadIdx.x + i * 256;
        out[(size_t)r * DMODEL + c] = (v[i] - mean) * inv * w[c] + b[c];
    }
}

// ---------------- weight transpose + bf16 hi/lo split ---------------------
// in : W[K][N] fp32 ; out: TH[N][K], TL[N][K] bf16 (RNE hi, RNE lo)
__global__ __launch_bounds__(256) void wconv(
    const float* __restrict__ W, unsigned short* __restrict__ TH,
    unsigned short* __restrict__ TL, int K, int N)
{
    __shared__ float t[32][33];
    int tx = threadIdx.x & 31, ty = threadIdx.x >> 5;  // ty 0..7
    int kb = blockIdx.y * 32, nb = blockIdx.x * 32;
    #pragma unroll
    for (int i = 0; i < 4; ++i) {
        int k = kb + ty + i * 8, n = nb + tx;
        t[ty + i * 8][tx] = (k < K && n < N) ? W[(size_t)k * N + n] : 0.f;
    }
    __syncthreads();
    #pragma unroll
    for (int i = 0; i < 4; ++i) {
        int n = nb + ty + i * 8, k = kb + tx;
        if (n < N && k < K) {
            float v = t[tx][ty + i * 8];
            unsigned u = __float_as_uint(v);
            unsigned rr = u + 0x7FFFu + ((u >> 16) & 1u);
            unsigned short hi = (unsigned short)(rr >> 16);
            float rem = v - __uint_as_float(((unsigned)hi) << 16);
            unsigned u2 = __float_as_uint(rem);
            unsigned r2 = u2 + 0x7FFFu + ((u2 >> 16) & 1u);
            unsigned short lo = (unsigned short)(r2 >> 16);
            TH[(size_t)n * K + k] = hi;
            TL[(size_t)n * K + k] = lo;
        }
    }
}

// ---------------- bf16x3 split-GEMM via MFMA (32x32x16) -------------------
// C[M,N] = A[M,K] @ B[K,N] (+bias, +gelu), fp32 in/out, ~fp32 precision.
// A: fp32 [M][lda], split hi/lo on the fly during LDS staging.
// B: pre-split/transposed bf16 BH/BL with layout [N][K].
// 128x128 tile, BK=32, 4 waves (2x2 quadrants of 64x64), each quadrant =
// 2x2 tiles of 32x32; v_mfma_f32_32x32x16_bf16, 3 MFMA per hi/lo pair.
__global__ __launch_bounds__(256) void gemm3(
    const float* __restrict__ Ag,
    const unsigned short* __restrict__ BHg, const unsigned short* __restrict__ BLg,
    float* __restrict__ C, const float* __restrict__ bias,
    int M, int N, int K, int lda, int ldc, int coloff,
    int revA, int revC, int act)
{
    // padded stride 40 bf16 = 80 B: 16B-aligned rows, 2-way-banked frag reads
    __shared__ unsigned short AsH[128 * 40], AsL[128 * 40];
    __shared__ unsigned short BsH[128 * 40], BsL[128 * 40];

    const int tid = threadIdx.x;
    const int m0 = blockIdx.y * 128;
    const int n0 = blockIdx.x * 128;

    // staging assignment: row r = tid>>1 (0..127), k-halves sg = 0 or 16
    const int r  = tid >> 1;
    const int sg = (tid & 1) * 16;
    int arow = m0 + r;
    if (revA) arow = (arow & ~(SEQ - 1)) + (SEQ - 1 - (arow & (SEQ - 1)));
    const size_t abase = (size_t)arow * lda;
    const int brow = n0 + r;
    const bool bok = brow < N;
    const size_t bbase = (size_t)brow * K;

    float4 fa[4];
    bhalf8 rb0, rb1, rb2, rb3;
    const bhalf8 bz = {0, 0, 0, 0, 0, 0, 0, 0};

    auto gload = [&](int k0) {
        size_t ao = abase + k0 + sg;
        #pragma unroll
        for (int q = 0; q < 4; ++q) fa[q] = *(const float4*)(Ag + ao + 4 * q);
        if (bok) {
            size_t bo = bbase + k0 + sg;
            rb0 = *(const bhalf8*)(BHg + bo);
            rb1 = *(const bhalf8*)(BHg + bo + 8);
            rb2 = *(const bhalf8*)(BLg + bo);
            rb3 = *(const bhalf8*)(BLg + bo + 8);
        } else { rb0 = bz; rb1 = bz; rb2 = bz; rb3 = bz; }
    };

    auto stage = [&]() {
        const float* fs = (const float*)fa;
        bhalf8 h0, h1, l0, l1;
        #pragma unroll
        for (int e = 0; e < 8; ++e) {
            unsigned short h, l;
            splitT(fs[e], h, l);     h0[e] = (short)h; l0[e] = (short)l;
            splitT(fs[8 + e], h, l); h1[e] = (short)h; l1[e] = (short)l;
        }
        *(bhalf8*)&AsH[r * 40 + sg]     = h0;
        *(bhalf8*)&AsH[r * 40 + sg + 8] = h1;
        *(bhalf8*)&AsL[r * 40 + sg]     = l0;
        *(bhalf8*)&AsL[r * 40 + sg + 8] = l1;
        *(bhalf8*)&BsH[r * 40 + sg]     = rb0;
        *(bhalf8*)&BsH[r * 40 + sg + 8] = rb1;
        *(bhalf8*)&BsL[r * 40 + sg]     = rb2;
        *(bhalf8*)&BsL[r * 40 + sg + 8] = rb3;
    };

    // wave layout: 2x2 waves; each wave owns a 64x64 quadrant = 2x2 32-tiles
    const int w = tid >> 6, lane = tid & 63;
    const int rw = (w >> 1) * 64, cw = (w & 1) * 64;
    const int lr = lane & 31;   // row/col within 32-tile
    const int lh = lane >> 5;   // k-half selector (0/1)

    floatx16 acc[2][2];
    #pragma unroll
    for (int i = 0; i < 2; ++i)
        #pragma unroll
        for (int j = 0; j < 2; ++j)
            #pragma unroll
            for (int e = 0; e < 16; ++e) acc[i][j][e] = 0.f;

    const int ktiles = K >> 5;   // K % 32 == 0 for all our GEMMs
    gload(0);
    for (int kt = 0; kt < ktiles; ++kt) {
        __syncthreads();
        stage();
        __syncthreads();
        if (kt + 1 < ktiles) gload((kt + 1) * 32);

        // two K=16 sub-steps within the K=32 LDS tile
        #pragma unroll
        for (int s = 0; s < 2; ++s) {
            const int ko = s * 16 + lh * 8;   // ushort offset within row
            bhalf8 ah[2], al[2], bhf[2], blf[2];
            #pragma unroll
            for (int i = 0; i < 2; ++i) {
                ah[i]  = *(const bhalf8*)&AsH[(rw + i * 32 + lr) * 40 + ko];
                al[i]  = *(const bhalf8*)&AsL[(rw + i * 32 + lr) * 40 + ko];
                bhf[i] = *(const bhalf8*)&BsH[(cw + i * 32 + lr) * 40 + ko];
                blf[i] = *(const bhalf8*)&BsL[(cw + i * 32 + lr) * 40 + ko];
            }
            #pragma unroll
            for (int i = 0; i < 2; ++i)
                #pragma unroll
                for (int j = 0; j < 2; ++j) {
                    acc[i][j] = __builtin_amdgcn_mfma_f32_32x32x16_bf16(ah[i], bhf[j], acc[i][j], 0, 0, 0);
                    acc[i][j] = __builtin_amdgcn_mfma_f32_32x32x16_bf16(ah[i], blf[j], acc[i][j], 0, 0, 0);
                    acc[i][j] = __builtin_amdgcn_mfma_f32_32x32x16_bf16(al[i], bhf[j], acc[i][j], 0, 0, 0);
                }
        }
    }

    // epilogue: 32x32 C/D layout col=lane&31, row=(reg&3)+8*(reg>>2)+4*(lane>>5)
    #pragma unroll
    for (int i = 0; i < 2; ++i) {
        #pragma unroll
        for (int j = 0; j < 2; ++j) {
            int gc = n0 + cw + j * 32 + lr;
            if (gc < N) {
                float bv = bias ? bias[gc] : 0.f;
                #pragma unroll
                for (int rg = 0; rg < 16; ++rg) {
                    int lrow = (rg & 3) + 8 * (rg >> 2) + 4 * lh;
                    int gm = m0 + rw + i * 32 + lrow;
                    if (revC) gm = (gm & ~(SEQ - 1)) + (SEQ - 1 - (gm & (SEQ - 1)));
                    float v = acc[i][j][rg] + bv;
                    if (act) v = gelu_f(v);
                    C[(size_t)gm * ldc + coloff + gc] = v;
                }
            }
        }
    }
}

// ---------------- depthwise causal conv + SiLU, fused dt/dA ---------------
// block.x covers 256 channels; spare threads in the last block (c in
// [CONVDIM, CONVDIM+NHEADS)) compute dt = softplus(zdt + bias) and dA.
__global__ __launch_bounds__(256) void conv_kernel(
    const float* __restrict__ zx, const float* __restrict__ cw,
    const float* __restrict__ cb, const float* __restrict__ dt_bias,
    const float* __restrict__ A_log, float* __restrict__ xcv,
    float* __restrict__ bc, float* __restrict__ dtda)
{
    int c = blockIdx.x * 256 + threadIdx.x;
    int r = blockIdx.y;
    if (c < CONVDIM) {
        int t = r & (SEQ - 1);
        int rb = r & ~(SEQ - 1);
        float acc = cb[c];
        #pragma unroll
        for (int k = 0; k < DCONV; ++k) {
            int tt = t - (DCONV - 1) + k;
            if (tt >= 0)
                acc += cw[c * DCONV + k] * zx[(size_t)(rb + tt) * DINPROJ + DINNER + c];
        }
        float v = acc / (1.0f + expf(-acc));   // silu
        if (c < DINNER) xcv[(size_t)r * DINNER + c] = v;
        else            bc[(size_t)r * 32 + (c - DINNER)] = v;
    } else if (c < CONVDIM + NHEADS) {
        int h = c - CONVDIM;
        float v = zx[(size_t)r * DINPROJ + (DINPROJ - NHEADS) + h] + dt_bias[h];
        float dt = (v > 20.f) ? v : log1pf(expf(v));
        float A = -expf(A_log[h]);
        dtda[(size_t)r * 48 + h] = dt;
        dtda[(size_t)r * 48 + 24 + h] = expf(dt * A);
    }
}

// ---------------- chunked scan, phase A: per-chunk local scan -------------
__global__ __launch_bounds__(64) void scan_a(
    const float* __restrict__ xcv, const float* __restrict__ bc,
    const float* __restrict__ dtda, const float* __restrict__ Dp,
    float* __restrict__ yout, float* __restrict__ S, float* __restrict__ cd)
{
    int blk = blockIdx.x;
    int bh = blk / NCHUNK, c = blk - bh * NCHUNK;
    int b = bh / NHEADS, h = bh - b * NHEADS;
    int p = threadIdx.x;
    float hs[DSTATE] = {};
    float Dv = Dp[h];
    float cum = 1.f;
    int t0 = c * QCH;
    for (int t = t0; t < t0 + QCH; ++t) {
        size_t r = (size_t)b * SEQ + t;
        float dt = dtda[r * 48 + h];
        float dA = dtda[r * 48 + 24 + h];
        float x  = xcv[r * DINNER + h * HEADDIM + p];
        cum *= dA;
        float coef = dt * x;
        const float* bcr = bc + r * 32;
        float y = 0.f;
        #pragma unroll
        for (int n = 0; n < DSTATE; ++n) {
            hs[n] = hs[n] * dA + coef * bcr[n];
            y += hs[n] * bcr[16 + n];
        }
        yout[r * DINPROJ + DINNER + h * HEADDIM + p] = y + Dv * x;
        if (p == 0) cd[r * NHEADS + h] = cum;
    }
    float* Sp = S + (((size_t)bh * NCHUNK + c) * HEADDIM + p) * DSTATE;
    #pragma unroll
    for (int n = 0; n < DSTATE; ++n) Sp[n] = hs[n];
}

// ---------------- chunked scan, phase B: sequential chunk combine ---------
__global__ __launch_bounds__(64) void scan_b(
    const float* __restrict__ cd, float* __restrict__ S)
{
    int bh = blockIdx.x;
    int b = bh / NHEADS, h = bh - b * NHEADS;
    int p = threadIdx.x;
    float H[DSTATE] = {};
    for (int c = 0; c < NCHUNK; ++c) {
        float* Sp = S + (((size_t)bh * NCHUNK + c) * HEADDIM + p) * DSTATE;
        float P = cd[((size_t)b * SEQ + c * QCH + QCH - 1) * NHEADS + h];
        float s[DSTATE];
        #pragma unroll
        for (int n = 0; n < DSTATE; ++n) s[n] = Sp[n];
        #pragma unroll
        for (int n = 0; n < DSTATE; ++n) Sp[n] = H[n];
        #pragma unroll
        for (int n = 0; n < DSTATE; ++n) H[n] = P * H[n] + s[n];
    }
}

// ---------------- chunked scan, phase C: carry correction -----------------
__global__ __launch_bounds__(64) void scan_c(
    const float* __restrict__ bc, const float* __restrict__ cd,
    const float* __restrict__ S, float* __restrict__ yout)
{
    int blk = blockIdx.x;
    int bh = blk / (NCHUNK - 1), c = blk - bh * (NCHUNK - 1) + 1;
    int b = bh / NHEADS, h = bh - b * NHEADS;
    int p = threadIdx.x;
    const float* Hp = S + (((size_t)bh * NCHUNK + c) * HEADDIM + p) * DSTATE;
    float H[DSTATE];
    #pragma unroll
    for (int n = 0; n < DSTATE; ++n) H[n] = Hp[n];
    int t0 = c * QCH;
    for (int t = t0; t < t0 + QCH; ++t) {
        size_t r = (size_t)b * SEQ + t;
        const float* Cr = bc + r * 32 + 16;
        float dot = 0.f;
        #pragma unroll
        for (int n = 0; n < DSTATE; ++n) dot += H[n] * Cr[n];
        float cum = cd[r * NHEADS + h];
        yout[r * DINPROJ + DINNER + h * HEADDIM + p] += cum * dot;
    }
}

// ---------------- gated RMSNorm: out = rmsnorm(y * silu(z)) * w -----------
__global__ __launch_bounds__(256) void gnorm_kernel(
    const float* __restrict__ zx, const float* __restrict__ nw,
    float* __restrict__ out)
{
    int r = blockIdx.x;
    const float* zr = zx + (size_t)r * DINPROJ;
    float v[6]; float ss = 0.f;
    #pragma unroll
    for (int i = 0; i < 6; ++i) {
        int c = threadIdx.x + i * 256;
        float z = zr[c];
        float y = zr[DINNER + c];
        float t = y * z / (1.0f + expf(-z));
        v[i] = t; ss += t * t;
    }
    float2 red = blockReduce2(ss, 0.f);
    float sc = rsqrtf(red.x * (1.0f / DINNER) + 1e-5f);
    #pragma unroll
    for (int i = 0; i < 6; ++i) {
        int c = threadIdx.x + i * 256;
        out[(size_t)r * DINNER + c] = v[i] * sc * nw[c];
    }
}

extern "C" void kernel_launch(void* const* d_in, const int* in_sizes, int n_in,
                              void* d_out, int out_size, void* d_ws, size_t ws_size,
                              hipStream_t stream)
{
    (void)in_sizes; (void)n_in; (void)out_size; (void)ws_size;
    const float* x     = (const float*)d_in[0];
    const float* ln1w  = (const float*)d_in[1];
    const float* ln1b  = (const float*)d_in[2];
    const float* ln2w  = (const float*)d_in[3];
    const float* ln2b  = (const float*)d_in[4];
    const float* ffnw1 = (const float*)d_in[5];
    const float* ffnb1 = (const float*)d_in[6];
    const float* ffnw2 = (const float*)d_in[7];
    const float* ffnb2 = (const float*)d_in[8];
    // per direction: in_w, conv_w, conv_b, dt_bias, A_log, D, norm_w, out_w
    const float* p[2][8];
    for (int d = 0; d < 2; ++d)
        for (int i = 0; i < 8; ++i)
            p[d][i] = (const float*)d_in[9 + d * 8 + i];

    // Workspace (215.7 MB — identical layout to the round-4/7 PASSING runs):
    //   zx   : 8192*3128 fp32 (102.5 MB); bi 50.3 MB; S 50.3 MB
    //   Wbuf : 2402304 floats (9.6 MB), also aliases Sbuf+cdbf during scan
    //   bcb / dtda : small
    float* ws   = (float*)d_ws;
    float* zx   = ws;
    float* bi   = zx + (size_t)ROWS * DINPROJ;
    float* S    = bi + (size_t)ROWS * DINNER;
    float* Wbuf = S  + (size_t)ROWS * DINNER;
    float* bcb  = Wbuf + 2402304;
    float* dtda = bcb + (size_t)ROWS * 32;
    float* Sbuf = Wbuf;                       // alias (dead in_proj weights)
    float* cdbf = Wbuf + (size_t)BATCH * NHEADS * NCHUNK * HEADDIM * DSTATE;
    float* xn   = (float*)d_out;
    float* xcv  = S;
    float* zn   = S;
    float* hmid = zx;
    float* ffo  = S + 4718592;   // after ffn1-weight region (18.9 MB)

    // 1. ln1: x -> xn (in d_out)
    ln_kernel<<<ROWS, 256, 0, stream>>>(x, nullptr, ln1w, ln1b, xn);

    for (int d = 0; d < 2; ++d) {
        unsigned short* WH = (unsigned short*)Wbuf;
        // in_proj weights: [768][3128] -> T [3128][768] hi/lo
        unsigned short* WL = WH + (size_t)DINPROJ * DMODEL;
        wconv<<<dim3((DINPROJ + 31) / 32, DMODEL / 32), 256, 0, stream>>>(
            p[d][0], WH, WL, DMODEL, DINPROJ);
        // 2. in_proj: zx = xn(flip if d==1) @ in_w   [8192 x 3128]
        gemm3<<<dim3((DINPROJ + 127) / 128, ROWS / 128), 256, 0, stream>>>(
            xn, WH, WL, zx, nullptr,
            ROWS, DINPROJ, DMODEL, DMODEL, DINPROJ, 0, d, 0, 0);
        // 3. conv + silu -> xcv, bcb; fused dt/dA -> dtda
        conv_kernel<<<dim3(7, ROWS), 256, 0, stream>>>(
            zx, p[d][1], p[d][2], p[d][3], p[d][4], xcv, bcb, dtda);
        // 4. chunked scan -> y (+D*x) into zx cols [1536,3072)
        //    (Sbuf/cdbf live in Wbuf — in_proj weights dead from here)
        scan_a<<<BATCH * NHEADS * NCHUNK, 64, 0, stream>>>(
            xcv, bcb, dtda, p[d][5], zx, Sbuf, cdbf);
        scan_b<<<BATCH * NHEADS, 64, 0, stream>>>(cdbf, Sbuf);
        scan_c<<<BATCH * NHEADS * (NCHUNK - 1), 64, 0, stream>>>(
            bcb, cdbf, Sbuf, zx);
        // 5. gated RMSNorm -> zn (xcv dead)
        gnorm_kernel<<<ROWS, 256, 0, stream>>>(zx, p[d][6], zn);
        // 6. out_proj: bi[:, d*768:(d+1)*768] = zn @ out_w, flip store if d==1
        //    (wconv rewrites Wbuf — scan buffers dead from here)
        unsigned short* WL2 = WH + (size_t)DMODEL * DINNER;
        wconv<<<dim3(DMODEL / 32, DINNER / 32), 256, 0, stream>>>(
            p[d][7], WH, WL2, DINNER, DMODEL);
        gemm3<<<dim3(DMODEL / 128, ROWS / 128), 256, 0, stream>>>(
            zn, WH, WL2, bi, nullptr,
            ROWS, DMODEL, DINNER, DINNER, DINNER, d * DMODEL, 0, d, 0);
    }

    // 7. ffn1: hmid = gelu(bi @ w1 + b1)  [8192 x 3072]; weights in S (zn dead)
    {
        unsigned short* WH = (unsigned short*)S;
        unsigned short* WL = WH + (size_t)DFFN * DINNER;
        wconv<<<dim3(DFFN / 32, DINNER / 32), 256, 0, stream>>>(
            ffnw1, WH, WL, DINNER, DFFN);
        gemm3<<<dim3(DFFN / 128, ROWS / 128), 256, 0, stream>>>(
            bi, WH, WL, hmid, ffnb1,
            ROWS, DFFN, DINNER, DINNER, DFFN, 0, 0, 0, 1);
    }
    // 8. ffn2: ffo = gelu(hmid @ w2 + b2) [8192 x 768]; weights in S (ffn1 wts dead)
    {
        unsigned short* WH = (unsigned short*)S;
        unsigned short* WL = WH + (size_t)DMODEL * DFFN;
        wconv<<<dim3(DMODEL / 32, DFFN / 32), 256, 0, stream>>>(
            ffnw2, WH, WL, DFFN, DMODEL);
        gemm3<<<dim3(DMODEL / 128, ROWS / 128), 256, 0, stream>>>(
            hmid, WH, WL, ffo, ffnb2,
            ROWS, DMODEL, DFFN, DFFN, DMODEL, 0, 0, 0, 1);
    }
    // 9. final layernorm(x + ffo) -> out
    ln_kernel<<<ROWS, 256, 0, stream>>>(x, ffo, ln2w, ln2b, (float*)d_out);
}